// Round 9
// baseline (2259.206 us; speedup 1.0000x reference)
//
#include <hip/hip_runtime.h>
#include <hip/hip_bf16.h>

// Problem constants
constexpr int H   = 8;
constexpr int B   = 32;
constexpr int SEQ = 4096;
constexpr int D   = 64;
constexpr int S   = 45;   // sample_k
constexpr int U   = 45;   // n_top
constexpr int HB  = H * B; // 256

// ---------------------------------------------------------------------------
// async global->LDS, 16B per lane. LDS dest is wave-uniform base (+lane*16 by
// HW); global src is per-lane.
// ---------------------------------------------------------------------------
__device__ __forceinline__ void stage16(const void* gsrc, void* ldst) {
    __builtin_amdgcn_global_load_lds(
        (const __attribute__((address_space(1))) unsigned int*)gsrc,
        (__attribute__((address_space(3))) unsigned int*)ldst,
        16, 0, 0);
}

// ---------------------------------------------------------------------------
// Kernel 1: sparsity measure M[hb][i] = max_s qk(i,s) - sum_s qk(i,s)/SEQ
// 4-lane query groups: lane holds 16 floats of D -> 2 shfl (not 4) per
// sample, 16 queries/wave. VALU ~180us hides under the ~310us vector-pipe
// floor (12 GB gather through 64 B/cyc/CU L1 return). PF=2 ring, indices in
// LDS with odd stride 49 (16 broadcast reads/wave -> 16 distinct banks).
// XCD remap (T1): hb === XCD (mod 8) keeps each hb's 1 MB K block L2-hot.
// ---------------------------------------------------------------------------
__global__ __launch_bounds__(256) void k_probe(const float* __restrict__ q,
                                               const float* __restrict__ k,
                                               const int* __restrict__ sidx,
                                               float* __restrict__ M) {
    __shared__ int sOff[64][49];     // byte offsets j*256, odd stride
    int xcd  = blockIdx.x & 7;       // dispatcher round-robins b%8 across XCDs
    int idx  = blockIdx.x >> 3;
    int qblk = idx & 63;             // 64 query-blocks per hb, fastest per XCD
    int hb   = (idx >> 6) * 8 + xcd; // 32 hb values per XCD, sequential
    int tid  = threadIdx.x;
    int g    = tid >> 2;             // group (query) 0..63
    int l    = tid & 3;              // 16-float slice id
    int i    = qblk * 64 + g;

    const int* ip = sidx + (size_t)i * S;
    for (int s = l; s < S; s += 4) sOff[g][s] = ip[s] << 8;   // *256 bytes
    __syncthreads();

    const float* qrow = q + ((size_t)hb * SEQ + i) * D + l * 16;
    float4 q0 = *(const float4*)(qrow);
    float4 q1 = *(const float4*)(qrow + 4);
    float4 q2 = *(const float4*)(qrow + 8);
    float4 q3 = *(const float4*)(qrow + 12);

    const char* kbase = (const char*)(k + (size_t)hb * SEQ * D) + l * 64;

    float4 buf[2][4];
#pragma unroll
    for (int p = 0; p < 2; ++p) {
        const char* kr = kbase + sOff[g][p];
        buf[p][0] = *(const float4*)(kr);
        buf[p][1] = *(const float4*)(kr + 16);
        buf[p][2] = *(const float4*)(kr + 32);
        buf[p][3] = *(const float4*)(kr + 48);
    }

    float mx = -1e30f, sm = 0.0f;
#pragma unroll
    for (int s = 0; s < S; ++s) {
        float4 k0 = buf[s & 1][0], k1 = buf[s & 1][1];
        float4 k2 = buf[s & 1][2], k3 = buf[s & 1][3];
        if (s + 2 < S) {             // compile-time under full unroll
            const char* kr = kbase + sOff[g][s + 2];
            buf[s & 1][0] = *(const float4*)(kr);
            buf[s & 1][1] = *(const float4*)(kr + 16);
            buf[s & 1][2] = *(const float4*)(kr + 32);
            buf[s & 1][3] = *(const float4*)(kr + 48);
        }
        float p = q0.x*k0.x + q0.y*k0.y + q0.z*k0.z + q0.w*k0.w
                + q1.x*k1.x + q1.y*k1.y + q1.z*k1.z + q1.w*k1.w
                + q2.x*k2.x + q2.y*k2.y + q2.z*k2.z + q2.w*k2.w
                + q3.x*k3.x + q3.y*k3.y + q3.z*k3.z + q3.w*k3.w;
        p += __shfl_xor(p, 1, 64);
        p += __shfl_xor(p, 2, 64);
        mx = fmaxf(mx, p);
        sm += p;
    }
    if (l == 0) M[(size_t)hb * SEQ + i] = mx - sm * (1.0f / (float)SEQ);
}

// ---------------------------------------------------------------------------
// Kernel 2: top-45 indices of M per (h,b). Iterative argmax, tie -> lower idx.
// ---------------------------------------------------------------------------
__global__ __launch_bounds__(256) void k_topk(const float* __restrict__ M,
                                              int* __restrict__ mtop) {
    __shared__ float sv[SEQ];
    __shared__ float rv[4];
    __shared__ int   ri[4];
    int hb = blockIdx.x;
    const float* Mr = M + (size_t)hb * SEQ;
    for (int t = threadIdx.x; t < SEQ; t += 256) sv[t] = Mr[t];
    __syncthreads();

    for (int t = 0; t < U; ++t) {
        float bv = -1e30f; int bi = 0;
        for (int c = threadIdx.x; c < SEQ; c += 256) {
            float vv = sv[c];
            if (vv > bv) { bv = vv; bi = c; }
        }
        for (int off = 32; off; off >>= 1) {
            float ov = __shfl_down(bv, off, 64);
            int   oi = __shfl_down(bi, off, 64);
            if (ov > bv || (ov == bv && oi < bi)) { bv = ov; bi = oi; }
        }
        int w = threadIdx.x >> 6;
        if ((threadIdx.x & 63) == 0) { rv[w] = bv; ri[w] = bi; }
        __syncthreads();
        if (threadIdx.x == 0) {
            for (int ww = 1; ww < 4; ++ww)
                if (rv[ww] > bv || (rv[ww] == bv && ri[ww] < bi)) { bv = rv[ww]; bi = ri[ww]; }
            mtop[hb * U + t] = bi;
            sv[bi] = -1e30f;
        }
        __syncthreads();
    }
}

// ---------------------------------------------------------------------------
// Kernel 3: fused per-(h,b) v-mean + broadcast fill of the whole output.
// ---------------------------------------------------------------------------
__global__ __launch_bounds__(1024) void k_vmeanfill(const float* __restrict__ v,
                                                    float* __restrict__ out) {
    int hb = blockIdx.x;
    int d  = threadIdx.x & 63;
    int r  = threadIdx.x >> 6;   // 0..15
    const float* vb = v + (size_t)hb * SEQ * D;
    float s = 0.0f;
    for (int i = r; i < SEQ; i += 16) s += vb[(size_t)i * D + d];
    __shared__ float sm[16][64];
    __shared__ float4 vmean4[16];
    sm[r][d] = s;
    __syncthreads();
    if (threadIdx.x < 64) {
        float t = 0.0f;
#pragma unroll
        for (int rr = 0; rr < 16; ++rr) t += sm[rr][d];
        ((float*)vmean4)[d] = t * (1.0f / (float)SEQ);
    }
    __syncthreads();
    float4 val = vmean4[threadIdx.x & 15];
    float* ob = out + (size_t)hb * SEQ * D;
    for (int t = threadIdx.x; t < SEQ * 16; t += 1024)
        *(float4*)(ob + (size_t)t * 4) = val;
}

// ---------------------------------------------------------------------------
// Kernel 4: attention for the 45 selected queries of one (h,b).
// 1024 threads = 16 waves; wave owns 3 queries and walks ALL 4096 keys.
// Lane = 8 key-groups x 8-float slices. 64-key K/V tiles staged into LDS via
// global_load_lds with XOR-swizzled source (col ^= (row&7)<<4); reads apply
// the same swizzle -> conflict-free ds_read_b128. Online softmax per tile;
// cross-group shfl reduce at the end; direct store (no merge).
// ---------------------------------------------------------------------------
#define QK8(p, qsrow, k0, k1)                                             \
    p = qsrow[0]*k0.x + qsrow[1]*k0.y + qsrow[2]*k0.z + qsrow[3]*k0.w     \
      + qsrow[4]*k1.x + qsrow[5]*k1.y + qsrow[6]*k1.z + qsrow[7]*k1.w;

__global__ __launch_bounds__(1024, 4) void k_attn(const float* __restrict__ q,
                                                  const float* __restrict__ k,
                                                  const float* __restrict__ v,
                                                  const int* __restrict__ mtop,
                                                  float* __restrict__ out) {
    __shared__ float KB[64][64];
    __shared__ float VB[64][64];
    int hb   = blockIdx.x;
    int tid  = threadIdx.x;
    int w    = tid >> 6;      // wave 0..15
    int lane = tid & 63;
    int grp  = lane >> 3;     // key-group 0..7
    int l    = lane & 7;      // 8-float slice id

    // --- this wave's 3 queries ---
    int u0 = w * 3, u1 = w * 3 + 1, u2 = w * 3 + 2;
    int uq0 = mtop[hb * U + (u0 < U ? u0 : U - 1)];
    int uq1 = mtop[hb * U + (u1 < U ? u1 : U - 1)];
    int uq2 = mtop[hb * U + (u2 < U ? u2 : U - 1)];
    const float* qb = q + (size_t)hb * SEQ * D;
    float qs0[8], qs1[8], qs2[8];
    {
        const float* r0 = qb + (size_t)uq0 * D + l * 8;
        const float* r1 = qb + (size_t)uq1 * D + l * 8;
        const float* r2 = qb + (size_t)uq2 * D + l * 8;
        float4 a, b4;
        a = *(const float4*)r0; b4 = *(const float4*)(r0 + 4);
        qs0[0]=a.x*0.125f; qs0[1]=a.y*0.125f; qs0[2]=a.z*0.125f; qs0[3]=a.w*0.125f;
        qs0[4]=b4.x*0.125f; qs0[5]=b4.y*0.125f; qs0[6]=b4.z*0.125f; qs0[7]=b4.w*0.125f;
        a = *(const float4*)r1; b4 = *(const float4*)(r1 + 4);
        qs1[0]=a.x*0.125f; qs1[1]=a.y*0.125f; qs1[2]=a.z*0.125f; qs1[3]=a.w*0.125f;
        qs1[4]=b4.x*0.125f; qs1[5]=b4.y*0.125f; qs1[6]=b4.z*0.125f; qs1[7]=b4.w*0.125f;
        a = *(const float4*)r2; b4 = *(const float4*)(r2 + 4);
        qs2[0]=a.x*0.125f; qs2[1]=a.y*0.125f; qs2[2]=a.z*0.125f; qs2[3]=a.w*0.125f;
        qs2[4]=b4.x*0.125f; qs2[5]=b4.y*0.125f; qs2[6]=b4.z*0.125f; qs2[7]=b4.w*0.125f;
    }

    // --- staging addresses (wave w stages rows 4w..4w+3 of each tile) ---
    const char* kg = (const char*)(k + (size_t)hb * SEQ * D);
    const char* vg = (const char*)(v + (size_t)hb * SEQ * D);
    int srow = 4 * w + (lane >> 4);
    size_t sgo = (size_t)srow * 256 + (size_t)(((lane & 15) * 16) ^ ((srow & 7) << 4));
    char* kl = (char*)KB + w * 1024;   // wave-uniform LDS dest
    char* vl = (char*)VB + w * 1024;

    float m0 = -1e30f, m1 = -1e30f, m2 = -1e30f;
    float ls0 = 0.0f, ls1 = 0.0f, ls2 = 0.0f;
    float O0[8], O1[8], O2[8];
#pragma unroll
    for (int d = 0; d < 8; ++d) { O0[d] = 0.0f; O1[d] = 0.0f; O2[d] = 0.0f; }

    const char* KBc = (const char*)KB;
    const char* VBc = (const char*)VB;
    int rb = (l * 32) ^ (grp << 4);   // swizzled col byte for this lane's keys

    for (int t = 0; t < 64; ++t) {
        stage16(kg + (size_t)t * 16384 + sgo, kl);
        stage16(vg + (size_t)t * 16384 + sgo, vl);
        __syncthreads();

        float s0[8], s1[8], s2[8];
#pragma unroll
        for (int sub = 0; sub < 8; ++sub) {
            int j = sub * 8 + grp;            // j&7 == grp
            const float4 ka = *(const float4*)(KBc + j * 256 + rb);
            const float4 kb2 = *(const float4*)(KBc + j * 256 + (rb ^ 16));
            float p0, p1, p2;
            QK8(p0, qs0, ka, kb2);
            QK8(p1, qs1, ka, kb2);
            QK8(p2, qs2, ka, kb2);
            p0 += __shfl_xor(p0, 1, 64); p0 += __shfl_xor(p0, 2, 64); p0 += __shfl_xor(p0, 4, 64);
            p1 += __shfl_xor(p1, 1, 64); p1 += __shfl_xor(p1, 2, 64); p1 += __shfl_xor(p1, 4, 64);
            p2 += __shfl_xor(p2, 1, 64); p2 += __shfl_xor(p2, 2, 64); p2 += __shfl_xor(p2, 4, 64);
            s0[sub] = p0; s1[sub] = p1; s2[sub] = p2;
        }
        // tile max per query (lane-local over 8 keys, then cross-group)
        float t0 = s0[0], t1 = s1[0], t2 = s2[0];
#pragma unroll
        for (int e = 1; e < 8; ++e) {
            t0 = fmaxf(t0, s0[e]); t1 = fmaxf(t1, s1[e]); t2 = fmaxf(t2, s2[e]);
        }
        t0 = fmaxf(t0, __shfl_xor(t0, 8, 64));  t0 = fmaxf(t0, __shfl_xor(t0, 16, 64)); t0 = fmaxf(t0, __shfl_xor(t0, 32, 64));
        t1 = fmaxf(t1, __shfl_xor(t1, 8, 64));  t1 = fmaxf(t1, __shfl_xor(t1, 16, 64)); t1 = fmaxf(t1, __shfl_xor(t1, 32, 64));
        t2 = fmaxf(t2, __shfl_xor(t2, 8, 64));  t2 = fmaxf(t2, __shfl_xor(t2, 16, 64)); t2 = fmaxf(t2, __shfl_xor(t2, 32, 64));
        float n0 = fmaxf(m0, t0), n1 = fmaxf(m1, t1), n2 = fmaxf(m2, t2);
        float c0 = __expf(m0 - n0), c1 = __expf(m1 - n1), c2 = __expf(m2 - n2);
        m0 = n0; m1 = n1; m2 = n2;
        ls0 *= c0; ls1 *= c1; ls2 *= c2;
#pragma unroll
        for (int d = 0; d < 8; ++d) { O0[d] *= c0; O1[d] *= c1; O2[d] *= c2; }

#pragma unroll
        for (int sub = 0; sub < 8; ++sub) {
            int j = sub * 8 + grp;
            const float4 va = *(const float4*)(VBc + j * 256 + rb);
            const float4 vb2 = *(const float4*)(VBc + j * 256 + (rb ^ 16));
            float p0 = __expf(s0[sub] - m0);
            float p1 = __expf(s1[sub] - m1);
            float p2 = __expf(s2[sub] - m2);
            ls0 += p0; ls1 += p1; ls2 += p2;
            O0[0] = fmaf(p0, va.x, O0[0]); O0[1] = fmaf(p0, va.y, O0[1]);
            O0[2] = fmaf(p0, va.z, O0[2]); O0[3] = fmaf(p0, va.w, O0[3]);
            O0[4] = fmaf(p0, vb2.x, O0[4]); O0[5] = fmaf(p0, vb2.y, O0[5]);
            O0[6] = fmaf(p0, vb2.z, O0[6]); O0[7] = fmaf(p0, vb2.w, O0[7]);
            O1[0] = fmaf(p1, va.x, O1[0]); O1[1] = fmaf(p1, va.y, O1[1]);
            O1[2] = fmaf(p1, va.z, O1[2]); O1[3] = fmaf(p1, va.w, O1[3]);
            O1[4] = fmaf(p1, vb2.x, O1[4]); O1[5] = fmaf(p1, vb2.y, O1[5]);
            O1[6] = fmaf(p1, vb2.z, O1[6]); O1[7] = fmaf(p1, vb2.w, O1[7]);
            O2[0] = fmaf(p2, va.x, O2[0]); O2[1] = fmaf(p2, va.y, O2[1]);
            O2[2] = fmaf(p2, va.z, O2[2]); O2[3] = fmaf(p2, va.w, O2[3]);
            O2[4] = fmaf(p2, vb2.x, O2[4]); O2[5] = fmaf(p2, vb2.y, O2[5]);
            O2[6] = fmaf(p2, vb2.z, O2[6]); O2[7] = fmaf(p2, vb2.w, O2[7]);
        }
        __syncthreads();   // all waves done reading before next stage
    }

    // --- reduce partial O / ls across the 8 key-groups ---
#pragma unroll
    for (int d = 0; d < 8; ++d) {
        O0[d] += __shfl_xor(O0[d], 8, 64);  O0[d] += __shfl_xor(O0[d], 16, 64); O0[d] += __shfl_xor(O0[d], 32, 64);
        O1[d] += __shfl_xor(O1[d], 8, 64);  O1[d] += __shfl_xor(O1[d], 16, 64); O1[d] += __shfl_xor(O1[d], 32, 64);
        O2[d] += __shfl_xor(O2[d], 8, 64);  O2[d] += __shfl_xor(O2[d], 16, 64); O2[d] += __shfl_xor(O2[d], 32, 64);
    }
    ls0 += __shfl_xor(ls0, 8, 64); ls0 += __shfl_xor(ls0, 16, 64); ls0 += __shfl_xor(ls0, 32, 64);
    ls1 += __shfl_xor(ls1, 8, 64); ls1 += __shfl_xor(ls1, 16, 64); ls1 += __shfl_xor(ls1, 32, 64);
    ls2 += __shfl_xor(ls2, 8, 64); ls2 += __shfl_xor(ls2, 16, 64); ls2 += __shfl_xor(ls2, 32, 64);

    float* ob = out + (size_t)hb * SEQ * D;
    if (grp == 0 && u0 < U) {
        float inv = 1.0f / ls0;
        float* p = ob + (size_t)uq0 * D + l * 8;
        *(float4*)(p)     = make_float4(O0[0]*inv, O0[1]*inv, O0[2]*inv, O0[3]*inv);
        *(float4*)(p + 4) = make_float4(O0[4]*inv, O0[5]*inv, O0[6]*inv, O0[7]*inv);
    }
    if (grp == 1 && u1 < U) {
        float inv = 1.0f / ls1;
        float* p = ob + (size_t)uq1 * D + l * 8;
        *(float4*)(p)     = make_float4(O1[0]*inv, O1[1]*inv, O1[2]*inv, O1[3]*inv);
        *(float4*)(p + 4) = make_float4(O1[4]*inv, O1[5]*inv, O1[6]*inv, O1[7]*inv);
    }
    if (grp == 2 && u2 < U) {
        float inv = 1.0f / ls2;
        float* p = ob + (size_t)uq2 * D + l * 8;
        *(float4*)(p)     = make_float4(O2[0]*inv, O2[1]*inv, O2[2]*inv, O2[3]*inv);
        *(float4*)(p + 4) = make_float4(O2[4]*inv, O2[5]*inv, O2[6]*inv, O2[7]*inv);
    }
}

// ---------------------------------------------------------------------------
extern "C" void kernel_launch(void* const* d_in, const int* in_sizes, int n_in,
                              void* d_out, int out_size, void* d_ws, size_t ws_size,
                              hipStream_t stream) {
    const float* q    = (const float*)d_in[0];
    const float* k    = (const float*)d_in[1];
    const float* v    = (const float*)d_in[2];
    const int*   sidx = (const int*)d_in[3];
    float* out = (float*)d_out;

    char* ws = (char*)d_ws;
    float* M    = (float*)ws;                         // 4 MB
    int*   mtop = (int*)(ws + (size_t)HB * SEQ * 4);  // 46 KB

    k_probe    <<<HB * (SEQ / 64), 256, 0, stream>>>(q, k, sidx, M);
    k_topk     <<<HB, 256,  0, stream>>>(M, mtop);
    k_vmeanfill<<<HB, 1024, 0, stream>>>(v, out);
    k_attn     <<<HB, 1024, 0, stream>>>(q, k, v, mtop, out);
}

// Round 10
// 1186.239 us; speedup vs baseline: 1.9045x; 1.9045x over previous
//
#include <hip/hip_runtime.h>
#include <hip/hip_bf16.h>

// Problem constants
constexpr int H   = 8;
constexpr int B   = 32;
constexpr int SEQ = 4096;
constexpr int D   = 64;
constexpr int S   = 45;   // sample_k
constexpr int U   = 45;   // n_top
constexpr int HB  = H * B; // 256

// ---------------------------------------------------------------------------
// async global->LDS, 16B per lane. LDS dest is wave-uniform base (+lane*16 by
// HW); global src is per-lane.
// ---------------------------------------------------------------------------
__device__ __forceinline__ void stage16(const void* gsrc, void* ldst) {
    __builtin_amdgcn_global_load_lds(
        (const __attribute__((address_space(1))) unsigned int*)gsrc,
        (__attribute__((address_space(3))) unsigned int*)ldst,
        16, 0, 0);
}

// ---------------------------------------------------------------------------
// Kernel 1: sparsity measure M[hb][i] = max_s qk(i,s) - sum_s qk(i,s)/SEQ
// ROUND-8 VERSION (verbatim revert; round-9's 4-lane layout was a 64-line-
// per-instruction coalescing regression). 16 groups x 16 lanes; group = one
// query; lane = float4 of D -> each load instruction touches 16 cache lines
// (4 rows x 4 contiguous). PF=4 ring keeps 4 gathers in flight per lane.
// XCD remap (T1): hb === XCD (mod 8) keeps each hb's 1 MB K block L2-hot.
// ---------------------------------------------------------------------------
__global__ __launch_bounds__(256) void k_probe(const float* __restrict__ q,
                                               const float* __restrict__ k,
                                               const int* __restrict__ sidx,
                                               float* __restrict__ M) {
    __shared__ int sIdx[16][48];
    int xcd  = blockIdx.x & 7;       // dispatcher round-robins b%8 across XCDs
    int idx  = blockIdx.x >> 3;
    int qblk = idx & 255;            // fastest-varying per XCD
    int hb   = (idx >> 8) * 8 + xcd; // 32 hb values per XCD, sequential
    int g    = threadIdx.x >> 4;
    int l    = threadIdx.x & 15;
    int i    = qblk * 16 + g;

    const int* ip = sidx + (size_t)i * S;
    sIdx[g][l]      = ip[l];
    sIdx[g][l + 16] = ip[l + 16];
    if (l + 32 < S) sIdx[g][l + 32] = ip[l + 32];
    __syncthreads();

    float4 qv = *(const float4*)(q + ((size_t)hb * SEQ + i) * D + l * 4);
    const float* kbase = k + (size_t)hb * SEQ * D;

    constexpr int PF = 4;            // ring depth: 16 VGPRs, fits 8 waves/SIMD
    float4 buf[PF];
#pragma unroll
    for (int p = 0; p < PF; ++p)
        buf[p] = *(const float4*)(kbase + (size_t)sIdx[g][p] * D + l * 4);

    float mx = -1e30f, sm = 0.0f;
#pragma unroll
    for (int s = 0; s < S; ++s) {
        float4 kv = buf[s % PF];
        if (s + PF < S)              // compile-time under full unroll
            buf[s % PF] = *(const float4*)(kbase + (size_t)sIdx[g][s + PF] * D + l * 4);
        float p = qv.x * kv.x + qv.y * kv.y + qv.z * kv.z + qv.w * kv.w;
        p += __shfl_xor(p, 8, 64);
        p += __shfl_xor(p, 4, 64);
        p += __shfl_xor(p, 2, 64);
        p += __shfl_xor(p, 1, 64);
        mx = fmaxf(mx, p);
        sm += p;
    }
    if (l == 0) M[(size_t)hb * SEQ + i] = mx - sm * (1.0f / (float)SEQ);
}

// ---------------------------------------------------------------------------
// Kernel 2: top-45 indices of M per (h,b). Iterative argmax, tie -> lower idx.
// ---------------------------------------------------------------------------
__global__ __launch_bounds__(256) void k_topk(const float* __restrict__ M,
                                              int* __restrict__ mtop) {
    __shared__ float sv[SEQ];
    __shared__ float rv[4];
    __shared__ int   ri[4];
    int hb = blockIdx.x;
    const float* Mr = M + (size_t)hb * SEQ;
    for (int t = threadIdx.x; t < SEQ; t += 256) sv[t] = Mr[t];
    __syncthreads();

    for (int t = 0; t < U; ++t) {
        float bv = -1e30f; int bi = 0;
        for (int c = threadIdx.x; c < SEQ; c += 256) {
            float vv = sv[c];
            if (vv > bv) { bv = vv; bi = c; }
        }
        for (int off = 32; off; off >>= 1) {
            float ov = __shfl_down(bv, off, 64);
            int   oi = __shfl_down(bi, off, 64);
            if (ov > bv || (ov == bv && oi < bi)) { bv = ov; bi = oi; }
        }
        int w = threadIdx.x >> 6;
        if ((threadIdx.x & 63) == 0) { rv[w] = bv; ri[w] = bi; }
        __syncthreads();
        if (threadIdx.x == 0) {
            for (int ww = 1; ww < 4; ++ww)
                if (rv[ww] > bv || (rv[ww] == bv && ri[ww] < bi)) { bv = rv[ww]; bi = ri[ww]; }
            mtop[hb * U + t] = bi;
            sv[bi] = -1e30f;
        }
        __syncthreads();
    }
}

// ---------------------------------------------------------------------------
// Kernel 3: fused per-(h,b) v-mean + broadcast fill of the whole output.
// ---------------------------------------------------------------------------
__global__ __launch_bounds__(1024) void k_vmeanfill(const float* __restrict__ v,
                                                    float* __restrict__ out) {
    int hb = blockIdx.x;
    int d  = threadIdx.x & 63;
    int r  = threadIdx.x >> 6;   // 0..15
    const float* vb = v + (size_t)hb * SEQ * D;
    float s = 0.0f;
    for (int i = r; i < SEQ; i += 16) s += vb[(size_t)i * D + d];
    __shared__ float sm[16][64];
    __shared__ float4 vmean4[16];
    sm[r][d] = s;
    __syncthreads();
    if (threadIdx.x < 64) {
        float t = 0.0f;
#pragma unroll
        for (int rr = 0; rr < 16; ++rr) t += sm[rr][d];
        ((float*)vmean4)[d] = t * (1.0f / (float)SEQ);
    }
    __syncthreads();
    float4 val = vmean4[threadIdx.x & 15];
    float* ob = out + (size_t)hb * SEQ * D;
    for (int t = threadIdx.x; t < SEQ * 16; t += 1024)
        *(float4*)(ob + (size_t)t * 4) = val;
}

// ---------------------------------------------------------------------------
// Kernel 4: attention for the 45 selected queries of one (h,b).
// NOW DOUBLE-BUFFERED (2-phase pipeline, T3-minimum): stage tile t+1 is
// issued BEFORE computing tile t, so the compiler's vmcnt(0)-before-barrier
// waits on loads whose HBM latency was hidden under compute. One barrier
// per iteration. LDS 2 x (16+16) KB.
// ---------------------------------------------------------------------------
#define QK8(p, qsrow, k0, k1)                                             \
    p = qsrow[0]*k0.x + qsrow[1]*k0.y + qsrow[2]*k0.z + qsrow[3]*k0.w     \
      + qsrow[4]*k1.x + qsrow[5]*k1.y + qsrow[6]*k1.z + qsrow[7]*k1.w;

__global__ __launch_bounds__(1024, 4) void k_attn(const float* __restrict__ q,
                                                  const float* __restrict__ k,
                                                  const float* __restrict__ v,
                                                  const int* __restrict__ mtop,
                                                  float* __restrict__ out) {
    __shared__ float KB[2][64][64];
    __shared__ float VB[2][64][64];
    int hb   = blockIdx.x;
    int tid  = threadIdx.x;
    int w    = tid >> 6;      // wave 0..15
    int lane = tid & 63;
    int grp  = lane >> 3;     // key-group 0..7
    int l    = lane & 7;      // 8-float slice id

    // --- this wave's 3 queries ---
    int u0 = w * 3, u1 = w * 3 + 1, u2 = w * 3 + 2;
    int uq0 = mtop[hb * U + (u0 < U ? u0 : U - 1)];
    int uq1 = mtop[hb * U + (u1 < U ? u1 : U - 1)];
    int uq2 = mtop[hb * U + (u2 < U ? u2 : U - 1)];
    const float* qb = q + (size_t)hb * SEQ * D;
    float qs0[8], qs1[8], qs2[8];
    {
        const float* r0 = qb + (size_t)uq0 * D + l * 8;
        const float* r1 = qb + (size_t)uq1 * D + l * 8;
        const float* r2 = qb + (size_t)uq2 * D + l * 8;
        float4 a, b4;
        a = *(const float4*)r0; b4 = *(const float4*)(r0 + 4);
        qs0[0]=a.x*0.125f; qs0[1]=a.y*0.125f; qs0[2]=a.z*0.125f; qs0[3]=a.w*0.125f;
        qs0[4]=b4.x*0.125f; qs0[5]=b4.y*0.125f; qs0[6]=b4.z*0.125f; qs0[7]=b4.w*0.125f;
        a = *(const float4*)r1; b4 = *(const float4*)(r1 + 4);
        qs1[0]=a.x*0.125f; qs1[1]=a.y*0.125f; qs1[2]=a.z*0.125f; qs1[3]=a.w*0.125f;
        qs1[4]=b4.x*0.125f; qs1[5]=b4.y*0.125f; qs1[6]=b4.z*0.125f; qs1[7]=b4.w*0.125f;
        a = *(const float4*)r2; b4 = *(const float4*)(r2 + 4);
        qs2[0]=a.x*0.125f; qs2[1]=a.y*0.125f; qs2[2]=a.z*0.125f; qs2[3]=a.w*0.125f;
        qs2[4]=b4.x*0.125f; qs2[5]=b4.y*0.125f; qs2[6]=b4.z*0.125f; qs2[7]=b4.w*0.125f;
    }

    // --- staging addresses (wave w stages rows 4w..4w+3 of each tile) ---
    const char* kg = (const char*)(k + (size_t)hb * SEQ * D);
    const char* vg = (const char*)(v + (size_t)hb * SEQ * D);
    int srow = 4 * w + (lane >> 4);
    size_t sgo = (size_t)srow * 256 + (size_t)(((lane & 15) * 16) ^ ((srow & 7) << 4));

    float m0 = -1e30f, m1 = -1e30f, m2 = -1e30f;
    float ls0 = 0.0f, ls1 = 0.0f, ls2 = 0.0f;
    float O0[8], O1[8], O2[8];
#pragma unroll
    for (int d = 0; d < 8; ++d) { O0[d] = 0.0f; O1[d] = 0.0f; O2[d] = 0.0f; }

    int rb = (l * 32) ^ (grp << 4);   // swizzled col byte for this lane's keys

    // --- prologue: stage tile 0 into buffer 0 ---
    stage16(kg + sgo, (char*)KB + w * 1024);
    stage16(vg + sgo, (char*)VB + w * 1024);
    __syncthreads();   // compiler drains vmcnt(0) here - tile 0 ready

    for (int t = 0; t < 64; ++t) {
        const char* KBc = (const char*)KB + (t & 1) * 16384;
        const char* VBc = (const char*)VB + (t & 1) * 16384;

        // issue next tile's stage BEFORE compute (latency hides under it)
        if (t < 63) {
            char* kd = (char*)KB + ((t + 1) & 1) * 16384 + w * 1024;
            char* vd = (char*)VB + ((t + 1) & 1) * 16384 + w * 1024;
            stage16(kg + (size_t)(t + 1) * 16384 + sgo, kd);
            stage16(vg + (size_t)(t + 1) * 16384 + sgo, vd);
        }

        float s0[8], s1[8], s2[8];
#pragma unroll
        for (int sub = 0; sub < 8; ++sub) {
            int j = sub * 8 + grp;            // j&7 == grp
            const float4 ka = *(const float4*)(KBc + j * 256 + rb);
            const float4 kb2 = *(const float4*)(KBc + j * 256 + (rb ^ 16));
            float p0, p1, p2;
            QK8(p0, qs0, ka, kb2);
            QK8(p1, qs1, ka, kb2);
            QK8(p2, qs2, ka, kb2);
            p0 += __shfl_xor(p0, 1, 64); p0 += __shfl_xor(p0, 2, 64); p0 += __shfl_xor(p0, 4, 64);
            p1 += __shfl_xor(p1, 1, 64); p1 += __shfl_xor(p1, 2, 64); p1 += __shfl_xor(p1, 4, 64);
            p2 += __shfl_xor(p2, 1, 64); p2 += __shfl_xor(p2, 2, 64); p2 += __shfl_xor(p2, 4, 64);
            s0[sub] = p0; s1[sub] = p1; s2[sub] = p2;
        }
        // tile max per query (lane-local over 8 keys, then cross-group)
        float t0 = s0[0], t1 = s1[0], t2 = s2[0];
#pragma unroll
        for (int e = 1; e < 8; ++e) {
            t0 = fmaxf(t0, s0[e]); t1 = fmaxf(t1, s1[e]); t2 = fmaxf(t2, s2[e]);
        }
        t0 = fmaxf(t0, __shfl_xor(t0, 8, 64));  t0 = fmaxf(t0, __shfl_xor(t0, 16, 64)); t0 = fmaxf(t0, __shfl_xor(t0, 32, 64));
        t1 = fmaxf(t1, __shfl_xor(t1, 8, 64));  t1 = fmaxf(t1, __shfl_xor(t1, 16, 64)); t1 = fmaxf(t1, __shfl_xor(t1, 32, 64));
        t2 = fmaxf(t2, __shfl_xor(t2, 8, 64));  t2 = fmaxf(t2, __shfl_xor(t2, 16, 64)); t2 = fmaxf(t2, __shfl_xor(t2, 32, 64));
        float n0 = fmaxf(m0, t0), n1 = fmaxf(m1, t1), n2 = fmaxf(m2, t2);
        float c0 = __expf(m0 - n0), c1 = __expf(m1 - n1), c2 = __expf(m2 - n2);
        m0 = n0; m1 = n1; m2 = n2;
        ls0 *= c0; ls1 *= c1; ls2 *= c2;
#pragma unroll
        for (int d = 0; d < 8; ++d) { O0[d] *= c0; O1[d] *= c1; O2[d] *= c2; }

#pragma unroll
        for (int sub = 0; sub < 8; ++sub) {
            int j = sub * 8 + grp;
            const float4 va = *(const float4*)(VBc + j * 256 + rb);
            const float4 vb2 = *(const float4*)(VBc + j * 256 + (rb ^ 16));
            float p0 = __expf(s0[sub] - m0);
            float p1 = __expf(s1[sub] - m1);
            float p2 = __expf(s2[sub] - m2);
            ls0 += p0; ls1 += p1; ls2 += p2;
            O0[0] = fmaf(p0, va.x, O0[0]); O0[1] = fmaf(p0, va.y, O0[1]);
            O0[2] = fmaf(p0, va.z, O0[2]); O0[3] = fmaf(p0, va.w, O0[3]);
            O0[4] = fmaf(p0, vb2.x, O0[4]); O0[5] = fmaf(p0, vb2.y, O0[5]);
            O0[6] = fmaf(p0, vb2.z, O0[6]); O0[7] = fmaf(p0, vb2.w, O0[7]);
            O1[0] = fmaf(p1, va.x, O1[0]); O1[1] = fmaf(p1, va.y, O1[1]);
            O1[2] = fmaf(p1, va.z, O1[2]); O1[3] = fmaf(p1, va.w, O1[3]);
            O1[4] = fmaf(p1, vb2.x, O1[4]); O1[5] = fmaf(p1, vb2.y, O1[5]);
            O1[6] = fmaf(p1, vb2.z, O1[6]); O1[7] = fmaf(p1, vb2.w, O1[7]);
            O2[0] = fmaf(p2, va.x, O2[0]); O2[1] = fmaf(p2, va.y, O2[1]);
            O2[2] = fmaf(p2, va.z, O2[2]); O2[3] = fmaf(p2, va.w, O2[3]);
            O2[4] = fmaf(p2, vb2.x, O2[4]); O2[5] = fmaf(p2, vb2.y, O2[5]);
            O2[6] = fmaf(p2, vb2.z, O2[6]); O2[7] = fmaf(p2, vb2.w, O2[7]);
        }
        __syncthreads();   // drains next-tile loads (covered) + read-safety
    }

    // --- reduce partial O / ls across the 8 key-groups ---
#pragma unroll
    for (int d = 0; d < 8; ++d) {
        O0[d] += __shfl_xor(O0[d], 8, 64);  O0[d] += __shfl_xor(O0[d], 16, 64); O0[d] += __shfl_xor(O0[d], 32, 64);
        O1[d] += __shfl_xor(O1[d], 8, 64);  O1[d] += __shfl_xor(O1[d], 16, 64); O1[d] += __shfl_xor(O1[d], 32, 64);
        O2[d] += __shfl_xor(O2[d], 8, 64);  O2[d] += __shfl_xor(O2[d], 16, 64); O2[d] += __shfl_xor(O2[d], 32, 64);
    }
    ls0 += __shfl_xor(ls0, 8, 64); ls0 += __shfl_xor(ls0, 16, 64); ls0 += __shfl_xor(ls0, 32, 64);
    ls1 += __shfl_xor(ls1, 8, 64); ls1 += __shfl_xor(ls1, 16, 64); ls1 += __shfl_xor(ls1, 32, 64);
    ls2 += __shfl_xor(ls2, 8, 64); ls2 += __shfl_xor(ls2, 16, 64); ls2 += __shfl_xor(ls2, 32, 64);

    float* ob = out + (size_t)hb * SEQ * D;
    if (grp == 0 && u0 < U) {
        float inv = 1.0f / ls0;
        float* p = ob + (size_t)uq0 * D + l * 8;
        *(float4*)(p)     = make_float4(O0[0]*inv, O0[1]*inv, O0[2]*inv, O0[3]*inv);
        *(float4*)(p + 4) = make_float4(O0[4]*inv, O0[5]*inv, O0[6]*inv, O0[7]*inv);
    }
    if (grp == 1 && u1 < U) {
        float inv = 1.0f / ls1;
        float* p = ob + (size_t)uq1 * D + l * 8;
        *(float4*)(p)     = make_float4(O1[0]*inv, O1[1]*inv, O1[2]*inv, O1[3]*inv);
        *(float4*)(p + 4) = make_float4(O1[4]*inv, O1[5]*inv, O1[6]*inv, O1[7]*inv);
    }
    if (grp == 2 && u2 < U) {
        float inv = 1.0f / ls2;
        float* p = ob + (size_t)uq2 * D + l * 8;
        *(float4*)(p)     = make_float4(O2[0]*inv, O2[1]*inv, O2[2]*inv, O2[3]*inv);
        *(float4*)(p + 4) = make_float4(O2[4]*inv, O2[5]*inv, O2[6]*inv, O2[7]*inv);
    }
}

// ---------------------------------------------------------------------------
extern "C" void kernel_launch(void* const* d_in, const int* in_sizes, int n_in,
                              void* d_out, int out_size, void* d_ws, size_t ws_size,
                              hipStream_t stream) {
    const float* q    = (const float*)d_in[0];
    const float* k    = (const float*)d_in[1];
    const float* v    = (const float*)d_in[2];
    const int*   sidx = (const int*)d_in[3];
    float* out = (float*)d_out;

    char* ws = (char*)d_ws;
    float* M    = (float*)ws;                         // 4 MB
    int*   mtop = (int*)(ws + (size_t)HB * SEQ * 4);  // 46 KB

    k_probe    <<<HB * (SEQ / 16), 256, 0, stream>>>(q, k, sidx, M);
    k_topk     <<<HB, 256,  0, stream>>>(M, mtop);
    k_vmeanfill<<<HB, 1024, 0, stream>>>(v, out);
    k_attn     <<<HB, 1024, 0, stream>>>(q, k, v, mtop, out);
}

// Round 11
// 1164.230 us; speedup vs baseline: 1.9405x; 1.0189x over previous
//
#include <hip/hip_runtime.h>
#include <hip/hip_bf16.h>

// Problem constants
constexpr int H   = 8;
constexpr int B   = 32;
constexpr int SEQ = 4096;
constexpr int D   = 64;
constexpr int S   = 45;   // sample_k
constexpr int U   = 45;   // n_top
constexpr int HB  = H * B; // 256

// ---------------------------------------------------------------------------
// async global->LDS, 16B per lane. LDS dest is wave-uniform base (+lane*16 by
// HW); global src is per-lane.
// ---------------------------------------------------------------------------
__device__ __forceinline__ void stage16(const void* gsrc, void* ldst) {
    __builtin_amdgcn_global_load_lds(
        (const __attribute__((address_space(1))) unsigned int*)gsrc,
        (__attribute__((address_space(3))) unsigned int*)ldst,
        16, 0, 0);
}

// ---------------------------------------------------------------------------
// Kernel 1: sparsity measure M[hb][i] = max_s qk(i,s) - sum_s qk(i,s)/SEQ
// FROZEN (round-8 version): 16 groups x 16 lanes, PF=4 ring, XCD remap (T1).
// 658 us @ 18.3 TB/s L2 gather.
// ---------------------------------------------------------------------------
__global__ __launch_bounds__(256) void k_probe(const float* __restrict__ q,
                                               const float* __restrict__ k,
                                               const int* __restrict__ sidx,
                                               float* __restrict__ M) {
    __shared__ int sIdx[16][48];
    int xcd  = blockIdx.x & 7;       // dispatcher round-robins b%8 across XCDs
    int idx  = blockIdx.x >> 3;
    int qblk = idx & 255;            // fastest-varying per XCD
    int hb   = (idx >> 8) * 8 + xcd; // 32 hb values per XCD, sequential
    int g    = threadIdx.x >> 4;
    int l    = threadIdx.x & 15;
    int i    = qblk * 16 + g;

    const int* ip = sidx + (size_t)i * S;
    sIdx[g][l]      = ip[l];
    sIdx[g][l + 16] = ip[l + 16];
    if (l + 32 < S) sIdx[g][l + 32] = ip[l + 32];
    __syncthreads();

    float4 qv = *(const float4*)(q + ((size_t)hb * SEQ + i) * D + l * 4);
    const float* kbase = k + (size_t)hb * SEQ * D;

    constexpr int PF = 4;            // ring depth: 16 VGPRs, fits 8 waves/SIMD
    float4 buf[PF];
#pragma unroll
    for (int p = 0; p < PF; ++p)
        buf[p] = *(const float4*)(kbase + (size_t)sIdx[g][p] * D + l * 4);

    float mx = -1e30f, sm = 0.0f;
#pragma unroll
    for (int s = 0; s < S; ++s) {
        float4 kv = buf[s % PF];
        if (s + PF < S)              // compile-time under full unroll
            buf[s % PF] = *(const float4*)(kbase + (size_t)sIdx[g][s + PF] * D + l * 4);
        float p = qv.x * kv.x + qv.y * kv.y + qv.z * kv.z + qv.w * kv.w;
        p += __shfl_xor(p, 8, 64);
        p += __shfl_xor(p, 4, 64);
        p += __shfl_xor(p, 2, 64);
        p += __shfl_xor(p, 1, 64);
        mx = fmaxf(mx, p);
        sm += p;
    }
    if (l == 0) M[(size_t)hb * SEQ + i] = mx - sm * (1.0f / (float)SEQ);
}

// ---------------------------------------------------------------------------
// Kernel 2: top-45 indices of M per (h,b). Iterative argmax, tie -> lower idx.
// ---------------------------------------------------------------------------
__global__ __launch_bounds__(256) void k_topk(const float* __restrict__ M,
                                              int* __restrict__ mtop) {
    __shared__ float sv[SEQ];
    __shared__ float rv[4];
    __shared__ int   ri[4];
    int hb = blockIdx.x;
    const float* Mr = M + (size_t)hb * SEQ;
    for (int t = threadIdx.x; t < SEQ; t += 256) sv[t] = Mr[t];
    __syncthreads();

    for (int t = 0; t < U; ++t) {
        float bv = -1e30f; int bi = 0;
        for (int c = threadIdx.x; c < SEQ; c += 256) {
            float vv = sv[c];
            if (vv > bv) { bv = vv; bi = c; }
        }
        for (int off = 32; off; off >>= 1) {
            float ov = __shfl_down(bv, off, 64);
            int   oi = __shfl_down(bi, off, 64);
            if (ov > bv || (ov == bv && oi < bi)) { bv = ov; bi = oi; }
        }
        int w = threadIdx.x >> 6;
        if ((threadIdx.x & 63) == 0) { rv[w] = bv; ri[w] = bi; }
        __syncthreads();
        if (threadIdx.x == 0) {
            for (int ww = 1; ww < 4; ++ww)
                if (rv[ww] > bv || (rv[ww] == bv && ri[ww] < bi)) { bv = rv[ww]; bi = ri[ww]; }
            mtop[hb * U + t] = bi;
            sv[bi] = -1e30f;
        }
        __syncthreads();
    }
}

// ---------------------------------------------------------------------------
// Kernel 3: attention + fused v-mean + output fill for one (h,b).
// 1024 threads = 16 waves; wave owns 3 queries, walks all 4096 keys.
// TRIPLE-buffered LDS (96 KB) with counted vmcnt + raw s_barrier (T4):
// stage(t+2) issued 2 tiles ahead; B1 = vmcnt(4)+barrier only forces the
// oldest tile's loads retired (no full drain -> HBM latency spans 2 compute
// phases). B2 barrier protects write-after-read of the recycled buffer.
// v-mean accumulated from the staged V tiles (free); epilogue fills the
// whole 1 MB output block with vmean then overwrites the 45 attn rows.
// ---------------------------------------------------------------------------
#define QK8(p, qsrow, k0, k1)                                             \
    p = qsrow[0]*k0.x + qsrow[1]*k0.y + qsrow[2]*k0.z + qsrow[3]*k0.w     \
      + qsrow[4]*k1.x + qsrow[5]*k1.y + qsrow[6]*k1.z + qsrow[7]*k1.w;

#define PIPE_BAR_PRE()  do { __builtin_amdgcn_s_barrier();                 \
                             __builtin_amdgcn_sched_barrier(0); } while (0)

__global__ __launch_bounds__(1024, 4) void k_attn(const float* __restrict__ q,
                                                  const float* __restrict__ k,
                                                  const float* __restrict__ v,
                                                  const int* __restrict__ mtop,
                                                  float* __restrict__ out) {
    __shared__ float KB[3][64][64];
    __shared__ float VB[3][64][64];
    int hb   = blockIdx.x;
    int tid  = threadIdx.x;
    int w    = tid >> 6;      // wave 0..15
    int lane = tid & 63;
    int grp  = lane >> 3;     // key-group 0..7
    int l    = lane & 7;      // 8-float slice id

    // --- this wave's 3 queries ---
    int u0 = w * 3, u1 = w * 3 + 1, u2 = w * 3 + 2;
    int uq0 = mtop[hb * U + (u0 < U ? u0 : U - 1)];
    int uq1 = mtop[hb * U + (u1 < U ? u1 : U - 1)];
    int uq2 = mtop[hb * U + (u2 < U ? u2 : U - 1)];
    const float* qb = q + (size_t)hb * SEQ * D;
    float qs0[8], qs1[8], qs2[8];
    {
        const float* r0 = qb + (size_t)uq0 * D + l * 8;
        const float* r1 = qb + (size_t)uq1 * D + l * 8;
        const float* r2 = qb + (size_t)uq2 * D + l * 8;
        float4 a, b4;
        a = *(const float4*)r0; b4 = *(const float4*)(r0 + 4);
        qs0[0]=a.x*0.125f; qs0[1]=a.y*0.125f; qs0[2]=a.z*0.125f; qs0[3]=a.w*0.125f;
        qs0[4]=b4.x*0.125f; qs0[5]=b4.y*0.125f; qs0[6]=b4.z*0.125f; qs0[7]=b4.w*0.125f;
        a = *(const float4*)r1; b4 = *(const float4*)(r1 + 4);
        qs1[0]=a.x*0.125f; qs1[1]=a.y*0.125f; qs1[2]=a.z*0.125f; qs1[3]=a.w*0.125f;
        qs1[4]=b4.x*0.125f; qs1[5]=b4.y*0.125f; qs1[6]=b4.z*0.125f; qs1[7]=b4.w*0.125f;
        a = *(const float4*)r2; b4 = *(const float4*)(r2 + 4);
        qs2[0]=a.x*0.125f; qs2[1]=a.y*0.125f; qs2[2]=a.z*0.125f; qs2[3]=a.w*0.125f;
        qs2[4]=b4.x*0.125f; qs2[5]=b4.y*0.125f; qs2[6]=b4.z*0.125f; qs2[7]=b4.w*0.125f;
    }

    // --- staging addresses (wave w stages rows 4w..4w+3 of each tile) ---
    const char* kg = (const char*)(k + (size_t)hb * SEQ * D);
    const char* vg = (const char*)(v + (size_t)hb * SEQ * D);
    int srow = 4 * w + (lane >> 4);
    size_t sgo = (size_t)srow * 256 + (size_t)(((lane & 15) * 16) ^ ((srow & 7) << 4));

    float m0 = -1e30f, m1 = -1e30f, m2 = -1e30f;
    float ls0 = 0.0f, ls1 = 0.0f, ls2 = 0.0f;
    float O0[8], O1[8], O2[8], vsum[8];
#pragma unroll
    for (int d = 0; d < 8; ++d) { O0[d]=0.0f; O1[d]=0.0f; O2[d]=0.0f; vsum[d]=0.0f; }

    int rb = (l * 32) ^ (grp << 4);   // swizzled col byte for this lane's keys

    // --- prologue: stage tiles 0 and 1 ---
    stage16(kg + sgo,         (char*)KB + 0 * 16384 + w * 1024);
    stage16(vg + sgo,         (char*)VB + 0 * 16384 + w * 1024);
    stage16(kg + 16384 + sgo, (char*)KB + 1 * 16384 + w * 1024);
    stage16(vg + 16384 + sgo, (char*)VB + 1 * 16384 + w * 1024);

    for (int t = 0; t < 64; ++t) {
        // issue stage(t+2) two tiles ahead (before the counted wait!)
        if (t < 62) {
            int bn = (t + 2) % 3;
            stage16(kg + (size_t)(t + 2) * 16384 + sgo, (char*)KB + bn * 16384 + w * 1024);
            stage16(vg + (size_t)(t + 2) * 16384 + sgo, (char*)VB + bn * 16384 + w * 1024);
        }
        // B1: wait only until tile t's loads retired, then barrier
        if (t < 62)      { asm volatile("s_waitcnt vmcnt(4)" ::: "memory"); }
        else if (t == 62){ asm volatile("s_waitcnt vmcnt(2)" ::: "memory"); }
        else             { asm volatile("s_waitcnt vmcnt(0)" ::: "memory"); }
        PIPE_BAR_PRE();

        const char* KBc = (const char*)KB + (t % 3) * 16384;
        const char* VBc = (const char*)VB + (t % 3) * 16384;

        float s0[8], s1[8], s2[8];
#pragma unroll
        for (int sub = 0; sub < 8; ++sub) {
            int j = sub * 8 + grp;            // j&7 == grp
            const float4 ka = *(const float4*)(KBc + j * 256 + rb);
            const float4 kb2 = *(const float4*)(KBc + j * 256 + (rb ^ 16));
            float p0, p1, p2;
            QK8(p0, qs0, ka, kb2);
            QK8(p1, qs1, ka, kb2);
            QK8(p2, qs2, ka, kb2);
            p0 += __shfl_xor(p0, 1, 64); p0 += __shfl_xor(p0, 2, 64); p0 += __shfl_xor(p0, 4, 64);
            p1 += __shfl_xor(p1, 1, 64); p1 += __shfl_xor(p1, 2, 64); p1 += __shfl_xor(p1, 4, 64);
            p2 += __shfl_xor(p2, 1, 64); p2 += __shfl_xor(p2, 2, 64); p2 += __shfl_xor(p2, 4, 64);
            s0[sub] = p0; s1[sub] = p1; s2[sub] = p2;
        }
        // tile max per query (lane-local over 8 keys, then cross-group)
        float t0 = s0[0], t1 = s1[0], t2 = s2[0];
#pragma unroll
        for (int e = 1; e < 8; ++e) {
            t0 = fmaxf(t0, s0[e]); t1 = fmaxf(t1, s1[e]); t2 = fmaxf(t2, s2[e]);
        }
        t0 = fmaxf(t0, __shfl_xor(t0, 8, 64));  t0 = fmaxf(t0, __shfl_xor(t0, 16, 64)); t0 = fmaxf(t0, __shfl_xor(t0, 32, 64));
        t1 = fmaxf(t1, __shfl_xor(t1, 8, 64));  t1 = fmaxf(t1, __shfl_xor(t1, 16, 64)); t1 = fmaxf(t1, __shfl_xor(t1, 32, 64));
        t2 = fmaxf(t2, __shfl_xor(t2, 8, 64));  t2 = fmaxf(t2, __shfl_xor(t2, 16, 64)); t2 = fmaxf(t2, __shfl_xor(t2, 32, 64));
        float n0 = fmaxf(m0, t0), n1 = fmaxf(m1, t1), n2 = fmaxf(m2, t2);
        float c0 = __expf(m0 - n0), c1 = __expf(m1 - n1), c2 = __expf(m2 - n2);
        m0 = n0; m1 = n1; m2 = n2;
        ls0 *= c0; ls1 *= c1; ls2 *= c2;
#pragma unroll
        for (int d = 0; d < 8; ++d) { O0[d] *= c0; O1[d] *= c1; O2[d] *= c2; }

#pragma unroll
        for (int sub = 0; sub < 8; ++sub) {
            int j = sub * 8 + grp;
            const float4 va = *(const float4*)(VBc + j * 256 + rb);
            const float4 vb2 = *(const float4*)(VBc + j * 256 + (rb ^ 16));
            // fused v-mean accumulation (each wave reads every row once/tile)
            vsum[0] += va.x;  vsum[1] += va.y;  vsum[2] += va.z;  vsum[3] += va.w;
            vsum[4] += vb2.x; vsum[5] += vb2.y; vsum[6] += vb2.z; vsum[7] += vb2.w;
            float p0 = __expf(s0[sub] - m0);
            float p1 = __expf(s1[sub] - m1);
            float p2 = __expf(s2[sub] - m2);
            ls0 += p0; ls1 += p1; ls2 += p2;
            O0[0] = fmaf(p0, va.x, O0[0]); O0[1] = fmaf(p0, va.y, O0[1]);
            O0[2] = fmaf(p0, va.z, O0[2]); O0[3] = fmaf(p0, va.w, O0[3]);
            O0[4] = fmaf(p0, vb2.x, O0[4]); O0[5] = fmaf(p0, vb2.y, O0[5]);
            O0[6] = fmaf(p0, vb2.z, O0[6]); O0[7] = fmaf(p0, vb2.w, O0[7]);
            O1[0] = fmaf(p1, va.x, O1[0]); O1[1] = fmaf(p1, va.y, O1[1]);
            O1[2] = fmaf(p1, va.z, O1[2]); O1[3] = fmaf(p1, va.w, O1[3]);
            O1[4] = fmaf(p1, vb2.x, O1[4]); O1[5] = fmaf(p1, vb2.y, O1[5]);
            O1[6] = fmaf(p1, vb2.z, O1[6]); O1[7] = fmaf(p1, vb2.w, O1[7]);
            O2[0] = fmaf(p2, va.x, O2[0]); O2[1] = fmaf(p2, va.y, O2[1]);
            O2[2] = fmaf(p2, va.z, O2[2]); O2[3] = fmaf(p2, va.w, O2[3]);
            O2[4] = fmaf(p2, vb2.x, O2[4]); O2[5] = fmaf(p2, vb2.y, O2[5]);
            O2[6] = fmaf(p2, vb2.z, O2[6]); O2[7] = fmaf(p2, vb2.w, O2[7]);
        }
        // B2: all waves done reading buf[t%3] before anyone re-stages it
        asm volatile("" ::: "memory");
        __builtin_amdgcn_s_barrier();
        __builtin_amdgcn_sched_barrier(0);
    }

    // --- reduce partial O / ls across the 8 key-groups ---
#pragma unroll
    for (int d = 0; d < 8; ++d) {
        O0[d] += __shfl_xor(O0[d], 8, 64);  O0[d] += __shfl_xor(O0[d], 16, 64); O0[d] += __shfl_xor(O0[d], 32, 64);
        O1[d] += __shfl_xor(O1[d], 8, 64);  O1[d] += __shfl_xor(O1[d], 16, 64); O1[d] += __shfl_xor(O1[d], 32, 64);
        O2[d] += __shfl_xor(O2[d], 8, 64);  O2[d] += __shfl_xor(O2[d], 16, 64); O2[d] += __shfl_xor(O2[d], 32, 64);
        vsum[d] += __shfl_xor(vsum[d], 8, 64); vsum[d] += __shfl_xor(vsum[d], 16, 64); vsum[d] += __shfl_xor(vsum[d], 32, 64);
    }
    ls0 += __shfl_xor(ls0, 8, 64); ls0 += __shfl_xor(ls0, 16, 64); ls0 += __shfl_xor(ls0, 32, 64);
    ls1 += __shfl_xor(ls1, 8, 64); ls1 += __shfl_xor(ls1, 16, 64); ls1 += __shfl_xor(ls1, 32, 64);
    ls2 += __shfl_xor(ls2, 8, 64); ls2 += __shfl_xor(ls2, 16, 64); ls2 += __shfl_xor(ls2, 32, 64);

    float* ob = out + (size_t)hb * SEQ * D;

    // --- fill this hb's whole output with vmean (wave w -> rows 256w..) ---
    float4 vm0, vm1;
    {
        float inv = 1.0f / (float)SEQ;
        vm0 = make_float4(vsum[0]*inv, vsum[1]*inv, vsum[2]*inv, vsum[3]*inv);
        vm1 = make_float4(vsum[4]*inv, vsum[5]*inv, vsum[6]*inv, vsum[7]*inv);
    }
    {
        int rbase = w * 256 + grp;
        for (int rr = 0; rr < 256; rr += 8) {
            float* p = ob + (size_t)(rbase + rr) * D + l * 8;
            *(float4*)(p)     = vm0;
            *(float4*)(p + 4) = vm1;
        }
    }
    __syncthreads();   // full drain: fill globally ordered before overwrite

    // --- scatter the 45 attended rows (overwrite) ---
    if (grp == 0 && u0 < U) {
        float inv = 1.0f / ls0;
        float* p = ob + (size_t)uq0 * D + l * 8;
        *(float4*)(p)     = make_float4(O0[0]*inv, O0[1]*inv, O0[2]*inv, O0[3]*inv);
        *(float4*)(p + 4) = make_float4(O0[4]*inv, O0[5]*inv, O0[6]*inv, O0[7]*inv);
    }
    if (grp == 1 && u1 < U) {
        float inv = 1.0f / ls1;
        float* p = ob + (size_t)uq1 * D + l * 8;
        *(float4*)(p)     = make_float4(O1[0]*inv, O1[1]*inv, O1[2]*inv, O1[3]*inv);
        *(float4*)(p + 4) = make_float4(O1[4]*inv, O1[5]*inv, O1[6]*inv, O1[7]*inv);
    }
    if (grp == 2 && u2 < U) {
        float inv = 1.0f / ls2;
        float* p = ob + (size_t)uq2 * D + l * 8;
        *(float4*)(p)     = make_float4(O2[0]*inv, O2[1]*inv, O2[2]*inv, O2[3]*inv);
        *(float4*)(p + 4) = make_float4(O2[4]*inv, O2[5]*inv, O2[6]*inv, O2[7]*inv);
    }
}

// ---------------------------------------------------------------------------
extern "C" void kernel_launch(void* const* d_in, const int* in_sizes, int n_in,
                              void* d_out, int out_size, void* d_ws, size_t ws_size,
                              hipStream_t stream) {
    const float* q    = (const float*)d_in[0];
    const float* k    = (const float*)d_in[1];
    const float* v    = (const float*)d_in[2];
    const int*   sidx = (const int*)d_in[3];
    float* out = (float*)d_out;

    char* ws = (char*)d_ws;
    float* M    = (float*)ws;                         // 4 MB
    int*   mtop = (int*)(ws + (size_t)HB * SEQ * 4);  // 46 KB

    k_probe<<<HB * (SEQ / 16), 256, 0, stream>>>(q, k, sidx, M);
    k_topk <<<HB, 256,  0, stream>>>(M, mtop);
    k_attn <<<HB, 1024, 0, stream>>>(q, k, v, mtop, out);
}